// Round 2
// baseline (358.173 us; speedup 1.0000x reference)
//
#include <hip/hip_runtime.h>
#include <stdint.h>

// Per-edge gathered 8x8 matvec, fp32 in / fp32 out.
// Thread-per-output: gid -> (edge = gid>>3, orow = gid&7).
// Coalescing: 8 lanes of one edge read the 256 B weight matrix contiguously
// (32 B/lane = two dwordx4); the 32 B x row broadcasts within the edge's
// 8 lanes (one cache line); output is 4 B/lane contiguous.

__global__ __launch_bounds__(256) void edge_linear_kernel(
    const float* __restrict__ values,    // fp32[NUM_VALUES][8]
    const float* __restrict__ weights,   // fp32[NUM_WEIGHTS][8][8]
    const int*   __restrict__ input_idx, // [E]
    const int*   __restrict__ weight_idx,// [E]
    float*       __restrict__ out,       // fp32[E][8]
    int E)
{
    int gid = blockIdx.x * blockDim.x + threadIdx.x;
    int e = gid >> 3;
    if (e >= E) return;
    int o = gid & 7;

    int iidx = input_idx[e];
    int widx = weight_idx[e];

    const float4* xp = (const float4*)(values  + (size_t)iidx * 8u);
    const float4* wp = (const float4*)(weights + (size_t)widx * 64u + (uint32_t)o * 8u);

    float4 x0 = xp[0];
    float4 x1 = xp[1];
    float4 w0 = wp[0];
    float4 w1 = wp[1];

    float acc = 0.0f;
    acc = fmaf(w0.x, x0.x, acc);
    acc = fmaf(w0.y, x0.y, acc);
    acc = fmaf(w0.z, x0.z, acc);
    acc = fmaf(w0.w, x0.w, acc);
    acc = fmaf(w1.x, x1.x, acc);
    acc = fmaf(w1.y, x1.y, acc);
    acc = fmaf(w1.z, x1.z, acc);
    acc = fmaf(w1.w, x1.w, acc);

    out[gid] = acc;
}

extern "C" void kernel_launch(void* const* d_in, const int* in_sizes, int n_in,
                              void* d_out, int out_size, void* d_ws, size_t ws_size,
                              hipStream_t stream) {
    const float* values     = (const float*)d_in[0];
    const float* weights    = (const float*)d_in[1];
    const int*   input_idx  = (const int*)d_in[2];
    const int*   weight_idx = (const int*)d_in[3];
    float*       out        = (float*)d_out;

    int E = in_sizes[2];              // 4194304 edges
    long long threads = (long long)E * 8;
    int block = 256;
    int grid = (int)((threads + block - 1) / block);

    edge_linear_kernel<<<grid, block, 0, stream>>>(values, weights, input_idx,
                                                   weight_idx, out, E);
}